// Round 2
// baseline (520.659 us; speedup 1.0000x reference)
//
#include <hip/hip_runtime.h>

#define NRAYS   262144
#define TCOARSE 64
#define NSAMP   256
#define RPB     32
#define TFINALF 1e10f
#define EPSF    1e-5f

__global__ __launch_bounds__(256) void informed_sampler_kernel(
    const float* __restrict__ tnear,
    const float* __restrict__ tfar,
    const float* __restrict__ dnorm,
    const float* __restrict__ density,
    const float* __restrict__ u,
    float* __restrict__ out)
{
    __shared__ float s_dens[TCOARSE * 33];            // [64][33] density tile
    __shared__ float s_sort[RPB * (NSAMP + 1)];       // [32][257] sorted staging
    __shared__ float s_cdf[RPB * 66];                 // [32][66]
    __shared__ float s_tn[RPB];
    __shared__ float s_td[RPB];

    const int tid  = threadIdx.x;
    const int lane = tid & 63;
    const int wid  = tid >> 6;
    const int r0   = blockIdx.x * RPB;

    if (tid < RPB) {
        float tn = tnear[r0 + tid];
        float tf = tfar [r0 + tid];
        s_tn[tid] = tn;
        s_td[tid] = tf - tn;
    }
    // stage density tile [TCOARSE][RPB] coalesced
    #pragma unroll
    for (int it = 0; it < 8; ++it) {
        int i = it * 8 + (tid >> 5);
        int c = tid & 31;
        s_dens[i * 33 + c] = density[i * NRAYS + r0 + c];
    }
    __syncthreads();

    // Phase 2: per-ray CDF. Wave wid handles rays c = k*4 + wid.
    #pragma unroll 1
    for (int k = 0; k < RPB / 4; ++k) {
        int c = k * 4 + wid;
        float tn = s_tn[c];
        float td = s_td[c];
        float dn = dnorm[r0 + c];
        float delta = (lane < TCOARSE - 1) ? td * (1.0f / 63.0f)
                                           : (TFINALF - (tn + td));
        float sd = s_dens[lane * 33 + c] * delta * dn;

        float inc = sd;                       // Kogge-Stone inclusive scan
        #pragma unroll
        for (int d = 1; d < 64; d <<= 1) {
            float o = __shfl_up(inc, d);
            if (lane >= d) inc += o;
        }
        // exclusive prefix WITHOUT cancellation: shift the inclusive scan
        float excl = __shfl_up(inc, 1);
        if (lane == 0) excl = 0.0f;
        float wv = __expf(-excl) * (1.0f - __expf(-sd)) + EPSF;

        float cw = wv;                        // inclusive scan of weights
        #pragma unroll
        for (int d = 1; d < 64; d <<= 1) {
            float o = __shfl_up(cw, d);
            if (lane >= d) cw += o;
        }
        float total = __shfl(cw, 63);
        s_cdf[c * 66 + lane + 1] = cw / total;
        if (lane == 0) s_cdf[c * 66] = 0.0f;
    }
    __syncthreads();

    // Phase 3: inverse-CDF sampling + wave bitonic sort (one wave per ray)
    #pragma unroll 1
    for (int k = 0; k < RPB / 4; ++k) {
        int c = k * 4 + wid;
        const float* cdfrow = &s_cdf[c * 66];
        float tn = s_tn[c];
        float td = s_td[c];
        float tf = tn + td;
        const float* urow = u + (size_t)(r0 + c) * NSAMP;
        float v[4];
        #pragma unroll
        for (int j = 0; j < 4; ++j) v[j] = urow[lane * 4 + j];

        #pragma unroll
        for (int j = 0; j < 4; ++j) {
            float uq = v[j];
            // searchsorted(cdf, u, side='right') over 65 entries
            int lo = 0, hi = TCOARSE + 1;
            #pragma unroll
            for (int itr = 0; itr < 7; ++itr) {
                int mid = (lo + hi) >> 1;
                bool go = (hi - lo) > 1;
                float cm = cdfrow[mid];
                if (go) { if (cm <= uq) lo = mid; else hi = mid; }
            }
            int b = min(hi, TCOARSE) - 1;     // bin 0..63
            float cb = cdfrow[b];
            float ca = cdfrow[b + 1];
            float denom = ca - cb;
            denom = (denom < EPSF) ? 1.0f : denom;
            float eb = (b == 0)  ? tn : tn + td * ((float)b - 0.5f) * (1.0f / 63.0f);
            float ea = (b == 63) ? tf : tn + td * ((float)b + 0.5f) * (1.0f / 63.0f);
            float smp = eb + ((uq - cb) / denom) * (ea - eb);
            // exact bounds of the interpolation; also absorbs NaN (minNum/maxNum)
            v[j] = fminf(fmaxf(smp, tn), tf);
        }

        // bitonic sort of 256 values across the wave; element e = lane*4 + j
        #pragma unroll
        for (int kk = 2; kk <= 256; kk <<= 1) {
            #pragma unroll
            for (int js = kk >> 1; js >= 4; js >>= 1) {
                int lxor = js >> 2;
                #pragma unroll
                for (int j = 0; j < 4; ++j) {
                    float other = __shfl_xor(v[j], lxor);
                    int e = lane * 4 + j;
                    bool asc   = ((e & kk) == 0);
                    bool lower = ((lane & lxor) == 0);
                    v[j] = (asc == lower) ? fminf(v[j], other) : fmaxf(v[j], other);
                }
            }
            if (kk >= 4) {                    // stride 2 (in-lane)
                #pragma unroll
                for (int j = 0; j < 2; ++j) {
                    int e = lane * 4 + j;
                    bool asc = ((e & kk) == 0);
                    float a = v[j], b2 = v[j + 2];
                    float mn = fminf(a, b2), mx = fmaxf(a, b2);
                    v[j] = asc ? mn : mx;
                    v[j + 2] = asc ? mx : mn;
                }
            }
            {                                 // stride 1 (in-lane)
                #pragma unroll
                for (int j = 0; j < 4; j += 2) {
                    int e = lane * 4 + j;
                    bool asc = ((e & kk) == 0);
                    float a = v[j], b2 = v[j + 1];
                    float mn = fminf(a, b2), mx = fmaxf(a, b2);
                    v[j] = asc ? mn : mx;
                    v[j + 1] = asc ? mx : mn;
                }
            }
        }

        float* srow = &s_sort[c * (NSAMP + 1)];
        #pragma unroll
        for (int j = 0; j < 4; ++j) srow[lane * 4 + j] = v[j];
    }
    __syncthreads();

    // Phase 4: transposed coalesced output, out[s*N + r]
    #pragma unroll 1
    for (int it = 0; it < 32; ++it) {
        int s = it * 8 + (tid >> 5);
        int c = tid & 31;
        out[(size_t)s * NRAYS + r0 + c] = s_sort[c * (NSAMP + 1) + s];
    }
}

extern "C" void kernel_launch(void* const* d_in, const int* in_sizes, int n_in,
                              void* d_out, int out_size, void* d_ws, size_t ws_size,
                              hipStream_t stream) {
    const float* tnear   = (const float*)d_in[0];
    const float* tfar    = (const float*)d_in[1];
    const float* dnorm   = (const float*)d_in[2];
    const float* density = (const float*)d_in[3];
    const float* u       = (const float*)d_in[4];
    float* out = (float*)d_out;

    dim3 grid(NRAYS / RPB);
    dim3 block(256);
    hipLaunchKernelGGL(informed_sampler_kernel, grid, block, 0, stream,
                       tnear, tfar, dnorm, density, u, out);
}

// Round 3
// 357.158 us; speedup vs baseline: 1.4578x; 1.4578x over previous
//
#include <hip/hip_runtime.h>

#define NRAYS   262144
#define TCOARSE 64
#define NSAMP   256
#define RPB     16
#define TFINALF 1e10f
#define EPSF    1e-5f

// ---- DPP helpers (VALU cross-lane, no DS pipe) ----
template<int CTRL, int RMASK = 0xF>
__device__ __forceinline__ float dppf(float x) {
    return __int_as_float(
        __builtin_amdgcn_update_dpp(0, __float_as_int(x), CTRL, RMASK, 0xF, false));
}

// wave64 inclusive +scan: 4 row_shr steps + row_bcast15/31 carries (classic GCN idiom)
__device__ __forceinline__ float wave_iscan(float x) {
    x += dppf<0x111>(x);           // row_shr:1
    x += dppf<0x112>(x);           // row_shr:2
    x += dppf<0x114>(x);           // row_shr:4
    x += dppf<0x118>(x);           // row_shr:8
    x += dppf<0x142, 0xA>(x);      // row_bcast15 -> rows 1,3
    x += dppf<0x143, 0xC>(x);      // row_bcast31 -> rows 2,3
    return x;
}

// butterfly exchange with lane^LX
template<int LX>
__device__ __forceinline__ float xchg(float x, int lane) {
    if constexpr (LX == 1)      return dppf<0xB1>(x);                 // quad_perm [1,0,3,2]
    else if constexpr (LX == 2) return dppf<0x4E>(x);                 // quad_perm [2,3,0,1]
    else if constexpr (LX == 4) {
        float a = dppf<0x104>(x);  // row_shl:4  out[l]=in[l+4]
        float b = dppf<0x114>(x);  // row_shr:4  out[l]=in[l-4]
        return (lane & 4) ? b : a;
    } else if constexpr (LX == 8) {
        float a = dppf<0x108>(x);  // row_shl:8
        float b = dppf<0x118>(x);  // row_shr:8
        return (lane & 8) ? b : a;
    } else {
        return __shfl_xor(x, LX);  // 16, 32: DS (row boundary)
    }
}

__device__ __forceinline__ void sort2c(float& a, float& b, bool asc) {
    float mn = fminf(a, b), mx = fmaxf(a, b);
    a = asc ? mn : mx;
    b = asc ? mx : mn;
}

template<int KK, int JS>
__device__ __forceinline__ void crosspass(float v[4], int lane, bool asc) {
    if constexpr (JS >= 4) {
        constexpr int LX = JS >> 2;
        bool keepmin = (asc == ((lane & LX) == 0));
        #pragma unroll
        for (int j = 0; j < 4; ++j) {
            float o = xchg<LX>(v[j], lane);
            float mn = fminf(v[j], o), mx = fmaxf(v[j], o);
            v[j] = keepmin ? mn : mx;
        }
        crosspass<KK, JS / 2>(v, lane, asc);
    }
}

template<int KK>
__device__ __forceinline__ void stage(float v[4], int lane) {
    bool asc = (lane & (KK >> 2)) == 0;    // ((e&KK)==0), e=4*lane+j, j-independent for KK>=8
    crosspass<KK, KK / 2>(v, lane, asc);
    sort2c(v[0], v[2], asc); sort2c(v[1], v[3], asc);   // stride 2 (in-lane)
    sort2c(v[0], v[1], asc); sort2c(v[2], v[3], asc);   // stride 1 (in-lane)
}

__device__ __forceinline__ void sort256(float v[4], int lane) {
    // stage kk=2: dirs compile-time (e&2 = j&2)
    { float mn = fminf(v[0], v[1]), mx = fmaxf(v[0], v[1]); v[0] = mn; v[1] = mx; }
    { float mn = fminf(v[2], v[3]), mx = fmaxf(v[2], v[3]); v[2] = mx; v[3] = mn; }
    // stage kk=4: asc = (lane&1)==0
    { bool asc = (lane & 1) == 0;
      sort2c(v[0], v[2], asc); sort2c(v[1], v[3], asc);
      sort2c(v[0], v[1], asc); sort2c(v[2], v[3], asc); }
    stage<8>(v, lane);  stage<16>(v, lane);  stage<32>(v, lane);
    stage<64>(v, lane); stage<128>(v, lane); stage<256>(v, lane);
}

__global__ __launch_bounds__(256, 6) void informed_sampler_kernel(
    const float* __restrict__ tnear,
    const float* __restrict__ tfar,
    const float* __restrict__ dnorm,
    const float* __restrict__ density,
    const float* __restrict__ u,
    float* __restrict__ out)
{
    __shared__ float s_dens[TCOARSE * (RPB + 1)];   // [64][17], conflict-free column reads
    __shared__ float s_sort[RPB * (NSAMP + 1)];     // [16][257]
    __shared__ float s_cdf[4 * 66];                 // one row per wave (wave-local reuse)
    __shared__ float s_tn[RPB], s_td[RPB], s_dn[RPB];

    const int tid  = threadIdx.x;
    const int lane = tid & 63;
    const int wid  = tid >> 6;
    const int r0   = blockIdx.x * RPB;

    if (tid < RPB) {
        float tn = tnear[r0 + tid];
        float tf = tfar [r0 + tid];
        s_tn[tid] = tn;
        s_td[tid] = tf - tn;
        s_dn[tid] = dnorm[r0 + tid];
    }
    #pragma unroll
    for (int it = 0; it < 4; ++it) {
        int i = it * 16 + (tid >> 4);
        int c = tid & 15;
        s_dens[i * (RPB + 1) + c] = density[(size_t)i * NRAYS + r0 + c];
    }
    __syncthreads();

    float* cdfrow = &s_cdf[wid * 66];

    #pragma unroll 1
    for (int k = 0; k < 4; ++k) {
        const int c = k * 4 + wid;
        const float tn = s_tn[c], td = s_td[c], dn = s_dn[c];
        const float tf = tn + td;

        // ---- CDF build (wave-parallel, DPP scans) ----
        float frac  = (float)lane * (1.0f / 63.0f);
        float tsl   = tn + td * frac;
        float tsn_  = tn + td * ((float)(lane + 1) * (1.0f / 63.0f));
        float delta = (lane < TCOARSE - 1) ? (tsn_ - tsl) : (TFINALF - tsl);
        float sd    = s_dens[lane * (RPB + 1) + c] * delta * dn;

        float inc  = wave_iscan(sd);
        float sh   = __shfl_up(inc, 1);
        float excl = (lane == 0) ? 0.0f : sh;      // exact exclusive (no cancellation)
        float wv   = expf(-excl) * (1.0f - expf(-sd)) + EPSF;

        float incw  = wave_iscan(wv);
        float total = __int_as_float(__builtin_amdgcn_readlane(__float_as_int(incw), 63));
        cdfrow[lane + 1] = incw / total;
        if (lane == 0) cdfrow[0] = 0.0f;
        asm volatile("s_waitcnt lgkmcnt(0)" ::: "memory");  // own writes visible to own reads

        // ---- inverse-CDF sampling ----
        const float4* u4 = reinterpret_cast<const float4*>(u) + (size_t)(r0 + c) * (NSAMP / 4);
        float4 uu = u4[lane];
        float v[4] = {uu.x, uu.y, uu.z, uu.w};

        #pragma unroll
        for (int j = 0; j < 4; ++j) {
            float uq = v[j];
            int b = 0;                               // last index with cdf[b] <= uq, b in [0,63]
            #pragma unroll
            for (int s = 32; s >= 1; s >>= 1)
                b += (cdfrow[b + s] <= uq) ? s : 0;
            float cb = cdfrow[b];
            float ca = cdfrow[b + 1];
            float denom = ca - cb;
            denom = (denom < EPSF) ? 1.0f : denom;
            float fb = (float)b;
            float eb = (b == 0)  ? tn : tn + td * ((fb - 0.5f) * (1.0f / 63.0f));
            float ea = (b == 63) ? tf : tn + td * ((fb + 0.5f) * (1.0f / 63.0f));
            float smp = eb + ((uq - cb) / denom) * (ea - eb);
            v[j] = fminf(fmaxf(smp, tn), tf);        // exact bounds; NaN-absorbing
        }

        // ---- wave bitonic sort (DPP exchanges, DS only for xor16/32) ----
        sort256(v, lane);

        float* srow = &s_sort[c * (NSAMP + 1)];
        #pragma unroll
        for (int j = 0; j < 4; ++j) srow[lane * 4 + j] = v[j];
    }
    __syncthreads();

    // ---- transposed coalesced output, out[s*N + r] ----
    #pragma unroll
    for (int it = 0; it < 16; ++it) {
        int s = it * 16 + (tid >> 4);
        int c = tid & 15;
        out[(size_t)s * NRAYS + r0 + c] = s_sort[c * (NSAMP + 1) + s];
    }
}

extern "C" void kernel_launch(void* const* d_in, const int* in_sizes, int n_in,
                              void* d_out, int out_size, void* d_ws, size_t ws_size,
                              hipStream_t stream) {
    const float* tnear   = (const float*)d_in[0];
    const float* tfar    = (const float*)d_in[1];
    const float* dnorm   = (const float*)d_in[2];
    const float* density = (const float*)d_in[3];
    const float* u       = (const float*)d_in[4];
    float* out = (float*)d_out;

    dim3 grid(NRAYS / RPB);
    dim3 block(256);
    hipLaunchKernelGGL(informed_sampler_kernel, grid, block, 0, stream,
                       tnear, tfar, dnorm, density, u, out);
}